// Round 5
// baseline (12875.880 us; speedup 1.0000x reference)
//
#include <hip/hip_runtime.h>
#include <hip/hip_cooperative_groups.h>
#include <stdint.h>

// Farthest point sampling: b=16, n=65536, npoints=2048. Full-f64 decision
// pipeline (R5: harness ref is float64 ground-truth recompute; R5-R20 absmax 0).
//
// R21 = R20 (4.31 ms) + XCD-local coherence for the slot protocol.
// R20's budget: ~5050 cy/iter of which ~3500 is publish->detect wait, whose
// largest constant is the LLC round trip (AGENT stores + sc0 sc1 polls are
// performed at the die-level LLC, ~900cy). The batch swizzle (bid&15=batch)
// already puts all 16 blocks of a batch at bids == g (mod 8) -> ONE XCD
// under round-robin dispatch. When that placement actually holds, the
// XCD's own L2 is a legal coherence point: publish with global_store sc0
// (performed at L2), poll with global_load_dwordx4 sc0 (L1-bypass, reads
// L2) -> ~300-400cy round trip instead of ~900.
// Placement is UNDEFINED by HIP, so it is VERIFIED at runtime: every block
// publishes s_getreg(HW_REG_XCC_ID) device-scope, grid.sync() (cooperative
// launch), each block checks all 16 IDs of its batch. Fast path only when
// verified; else the R20 protocol runs verbatim. Both paths keep the tag/
// parity/guard discipline -> no hang mode. Fast path: s_sleep(4) not (12).
// Tripwire: fast path active <=> WRITE_SIZE collapses (slot stores stop
// writing through to LLC/HBM).
// Everything else R20 verbatim: pre-widened f64 coords; DPP/permlane
// butterflies; per-wave publish of 16-B quarters; wave0 polls 64 quarters
// (own-quarter register substitution); speculative coord prefetch +
// ballot(si==ci) + readlane broadcast; waves1-3 spin on 3 self-tagged LDS
// coord words. Parity double-buffer, unique 16-bit tags, skew<=1.

#define NBATCH   16
#define NPTS     65536
#define NPOINTS  2048
#define KBLK     16                  // blocks per batch
#define THREADS  256
#define PPB      4096                // points per block
#define PPT      16                  // points per thread
#define QPB      4                   // quarters (waves) per block
#define SLOT_U64 2                   // 16 B per wave-quarter
#define REGION_U64 (KBLK * QPB * SLOT_U64) // 128 u64 = 1 KB per (parity,batch)
#define XID_OFF_U64 4096             // ID area at byte 32768 (past 2x16 regions)

#define TAGOK(w) (((unsigned)((w) >> 16) & 0xFFFFu) == tag)

namespace cg = cooperative_groups;

typedef unsigned int uint4v __attribute__((ext_vector_type(4)));
typedef unsigned int uint2v __attribute__((ext_vector_type(2)));

// One 16-B device-coherent load covering both quarter words (LLC path).
__device__ __forceinline__ void load_slot16(const unsigned long long* p,
                                            unsigned long long& w0,
                                            unsigned long long& w1) {
    uint4v r;
    asm volatile("global_load_dwordx4 %0, %1, off sc0 sc1\n\t"
                 "s_waitcnt vmcnt(0)"
                 : "=v"(r) : "v"(p) : "memory");
    w0 = ((unsigned long long)r.y << 32) | r.x;
    w1 = ((unsigned long long)r.w << 32) | r.z;
}

// Same, XCD-L2-coherent (L1 bypass only; legal when writer is same-XCD).
__device__ __forceinline__ void load_slot16_l2(const unsigned long long* p,
                                               unsigned long long& w0,
                                               unsigned long long& w1) {
    uint4v r;
    asm volatile("global_load_dwordx4 %0, %1, off sc0\n\t"
                 "s_waitcnt vmcnt(0)"
                 : "=v"(r) : "v"(p) : "memory");
    w0 = ((unsigned long long)r.y << 32) | r.x;
    w1 = ((unsigned long long)r.w << 32) | r.z;
}

// ---- argmax butterfly stages: (d,i) <- winner of self and partner ----
__device__ __forceinline__ void red_combine(double& d, int& i,
                                            double od, int oi) {
    const bool t = (od > d) || (od == d && oi < i);
    d = t ? od : d; i = t ? oi : i;
}

template <int CTRL>
__device__ __forceinline__ void red_dpp(double& d, int& i) {
    const int hi = __double2hiint(d), lo = __double2loint(d);
    const int ohi = __builtin_amdgcn_update_dpp(hi, hi, CTRL, 0xF, 0xF, false);
    const int olo = __builtin_amdgcn_update_dpp(lo, lo, CTRL, 0xF, 0xF, false);
    const int oi  = __builtin_amdgcn_update_dpp(i,  i,  CTRL, 0xF, 0xF, false);
    red_combine(d, i, __hiloint2double(ohi, olo), oi);
}

__device__ __forceinline__ void red_swz16(double& d, int& i) {
    // ds_swizzle BitMode xor16: offset = (16<<10) | 0x1F = 0x401F
    const int ohi = __builtin_amdgcn_ds_swizzle(__double2hiint(d), 0x401F);
    const int olo = __builtin_amdgcn_ds_swizzle(__double2loint(d), 0x401F);
    const int oi  = __builtin_amdgcn_ds_swizzle(i, 0x401F);
    red_combine(d, i, __hiloint2double(ohi, olo), oi);
}

__device__ __forceinline__ void red_x32(double& d, int& i, bool hi_half) {
    // permlane32_swap(v,v): partner = hi_half ? r[0] : r[1].
    const unsigned hi = (unsigned)__double2hiint(d);
    const unsigned lo = (unsigned)__double2loint(d);
    uint2v rh = __builtin_amdgcn_permlane32_swap(hi, hi, false, false);
    uint2v rl = __builtin_amdgcn_permlane32_swap(lo, lo, false, false);
    uint2v ri = __builtin_amdgcn_permlane32_swap((unsigned)i, (unsigned)i,
                                                 false, false);
    const int ohi = (int)(hi_half ? rh[0] : rh[1]);
    const int olo = (int)(hi_half ? rl[0] : rl[1]);
    const int oi  = (int)(hi_half ? ri[0] : ri[1]);
    red_combine(d, i, __hiloint2double(ohi, olo), oi);
}

// Full 64-lane argmax (all lanes end with the global winner). Stage order
// matters: mirrors rely on prior quad/8-group uniformity.
__device__ __forceinline__ void argmax64(double& d, int& i, bool hi_half) {
    red_dpp<0xB1>(d, i);    // xor1  (quad_perm 1,0,3,2)
    red_dpp<0x4E>(d, i);    // xor2  (quad_perm 2,3,0,1)
    red_dpp<0x141>(d, i);   // i^7 row_half_mirror -> 8-max
    red_dpp<0x140>(d, i);   // i^15 row_mirror     -> 16-max
    red_swz16(d, i);        // xor16               -> 32-max
    red_x32(d, i, hi_half); // xor32               -> 64-max
}

__global__ __launch_bounds__(THREADS, 1)
void fps_kernel(const float* __restrict__ pts, int* __restrict__ out,
                unsigned long long* __restrict__ slots, int allow_fast)
{
    const int bid  = blockIdx.x;
    const int g    = bid & 15;       // batch (XCD co-location swizzle)
    const int blk  = bid >> 4;       // block within batch, 0..15
    const int tid  = threadIdx.x;
    const int lane = tid & 63;
    const int wave = tid >> 6;       // 0..3
    const bool hi_half = (lane >= 32);

    const float* __restrict__ P = pts + (size_t)g * (NPTS * 3);

    // mailbox: [par][k] = coord_k|tag for k=0,1,2 (x,y,z); [3] unused pad
    __shared__ unsigned long long s_mail[2][4];

    // ---- one-time placement verification: is this batch single-XCD? ----
    int same_xcd = 0;
    if (allow_fast) {
        unsigned xid;
        asm volatile("s_getreg_b32 %0, hwreg(HW_REG_XCC_ID)" : "=s"(xid));
        xid &= 0xFu;
        unsigned* xa = (unsigned*)(slots + XID_OFF_U64);
        if (tid == 0)
            __hip_atomic_store(&xa[bid], 0xC0DE0000u | xid,
                               __ATOMIC_RELAXED, __HIP_MEMORY_SCOPE_AGENT);
        cg::this_grid().sync();      // device-scope fence + grid barrier
        unsigned ref = 0; bool same = true;
        for (int k = 0; k < KBLK; ++k) {
            const unsigned v = __hip_atomic_load(&xa[g + (k << 4)],
                                  __ATOMIC_RELAXED, __HIP_MEMORY_SCOPE_AGENT);
            if ((v >> 16) != 0xC0DEu) same = false;
            if (k == 0) ref = v; else same = same && (v == ref);
        }
        same_xcd = same ? 1 : 0;
    }

    // Pre-widened f64 coords (cvt paid ONCE, not per iteration) + f64 dist.
    double xd[PPT], yd[PPT], zd[PPT], dist[PPT];
    const int base = blk * PPB;
#pragma unroll
    for (int j = 0; j < PPT; ++j) {
        const int idx = base + j * THREADS + tid;
        xd[j] = (double)P[idx * 3 + 0];
        yd[j] = (double)P[idx * 3 + 1];
        zd[j] = (double)P[idx * 3 + 2];
        dist[j] = 1e10;              // never survives iteration 0
    }
    if (tid < 8) ((unsigned long long*)s_mail)[tid] = 0ull;  // tags never 0
    __syncthreads();                 // once, before the loop

    double qx = (double)P[0], qy = (double)P[1], qz = (double)P[2];
    if (blk == 0 && tid == 0) out[g * NPOINTS] = 0;

    for (int it = 0; it < NPOINTS - 1; ++it) {
        // ---- f64 min-dist update + thread-local argmax (first-max) ----
        double bd = -1.0;
        int    bi = 0x7FFFFFFF;
        {
#pragma clang fp contract(off)
#pragma unroll
            for (int j = 0; j < PPT; ++j) {
                const double dx = xd[j] - qx;
                const double dy = yd[j] - qy;
                const double dz = zd[j] - qz;
                const double d  = (dx * dx + dy * dy) + dz * dz;
                const double nd = fmin(dist[j], d);
                dist[j] = nd;
                const bool t = nd > bd;          // strict: first-max kept
                bd = t ? nd : bd;
                bi = t ? (base + j * THREADS + tid) : bi;
            }
        }

        // ---- 64-lane argmax butterfly (DPP/permlane transport) ----
        argmax64(bd, bi, hi_half);

        const unsigned tag = (unsigned)(it + 1);
        const int par = it & 1;
        unsigned long long* rb =
            slots + (size_t)(par * NBATCH + g) * REGION_U64;

        // ---- this wave's quarter words (publish + own substitution) ----
        const unsigned long long B =
            (unsigned long long)__double_as_longlong(bd);
        const unsigned long long TI =
              ((unsigned long long)tag << 16)
            | (unsigned long long)((unsigned)bi & 0xFFFFu);
        const unsigned long long own0 = ((B >> 32) << 32) | TI;
        const unsigned long long own1 = ((B & 0xFFFFFFFFull) << 32) | TI;

        // ---- per-wave publish: straight from butterfly to global store ----
        if (lane < 2) {
            unsigned long long* dst =
                rb + (blk * QPB + wave) * SLOT_U64 + lane;
            const unsigned long long v = (lane == 0) ? own0 : own1;
            if (same_xcd) {
                // performed at this XCD's L2 (the verified coherence point)
                asm volatile("global_store_dwordx2 %0, %1, off sc0"
                             :: "v"(dst), "v"(v) : "memory");
            } else {
                __hip_atomic_store(dst, v, __ATOMIC_RELAXED,
                                   __HIP_MEMORY_SCOPE_AGENT);
            }
        }

        float qxf, qyf, qzf;         // this iteration's winner coords (f32)

        if (wave != 0) {
            // ---- winner coords from LDS (3 self-tagged words). This IS
            //      the rendezvous; parity leftovers carry tag it-1 ----
            unsigned long long f1, f2, f3;
            int guard = 0;
            bool okm;
            do {
                f1 = __hip_atomic_load(&s_mail[par][0], __ATOMIC_RELAXED,
                                       __HIP_MEMORY_SCOPE_WORKGROUP);
                f2 = __hip_atomic_load(&s_mail[par][1], __ATOMIC_RELAXED,
                                       __HIP_MEMORY_SCOPE_WORKGROUP);
                f3 = __hip_atomic_load(&s_mail[par][2], __ATOMIC_RELAXED,
                                       __HIP_MEMORY_SCOPE_WORKGROUP);
                okm = ((unsigned)f1 == tag) & ((unsigned)f2 == tag)
                    & ((unsigned)f3 == tag);
            } while (!okm && ++guard < (1 << 20));
            qxf = __int_as_float((int)(f1 >> 32));
            qyf = __int_as_float((int)(f2 >> 32));
            qzf = __int_as_float((int)(f3 >> 32));
        } else {
            // ---- wave0: poll all 64 quarters, lane i watches quarter i.
            //      Own quarter (lane == blk*4) from registers. ----
            unsigned long long* sp = rb + lane * SLOT_U64;
            const bool own = (lane == blk * QPB);
            unsigned long long l0 = own0, l1 = own1;
            bool ok = own;
            if (same_xcd) {
                __builtin_amdgcn_s_sleep(4);   // ~256 cy: L2 visibility
                int g1 = 0;
                while (!ok && g1 < 48) {
                    load_slot16_l2(sp, l0, l1);
                    ok = TAGOK(l0) & TAGOK(l1);
                    ++g1;
                }
            } else {
                __builtin_amdgcn_s_sleep(12);  // ~768 cy: LLC visibility
                int g1 = 0;
                while (!ok && g1 < 32) {
                    load_slot16(sp, l0, l1);
                    ok = TAGOK(l0) & TAGOK(l1);
                    ++g1;
                }
            }
            int g2 = 0;
            while (!ok) {
                // escalation: proven agent atomic-pair spin (correct on
                // both paths; same-XCD requests are serviced via its L2)
                l0 = __hip_atomic_load(sp + 0, __ATOMIC_RELAXED,
                                       __HIP_MEMORY_SCOPE_AGENT);
                l1 = __hip_atomic_load(sp + 1, __ATOMIC_RELAXED,
                                       __HIP_MEMORY_SCOPE_AGENT);
                ok = TAGOK(l0) & TAGOK(l1);
                if (++g2 > (1 << 20)) break;   // fail loud, never hang
            }

            double cd = __longlong_as_double(
                (long long)(((l0 >> 32) << 32) | (l1 >> 32)));
            int    ci = (int)(l0 & 0xFFFFull);

            // ---- speculative prefetch of THIS lane's candidate coords:
            //      issued before the butterfly so the L2 hit overlaps it ----
            const int    si = ci;
            const float* pc = P + (size_t)(unsigned)si * 3;
            const float px = pc[0];
            const float py = pc[1];
            const float pz = pc[2];

            // ---- 64-quarter argmax butterfly (DPP/permlane transport) ----
            argmax64(cd, ci, hi_half);

            // ---- out write: independent of the coord chain ----
            if (lane == 0 && blk == 0) out[g * NPOINTS + it + 1] = ci;

            // ---- winning lane -> broadcast its prefetched coords.
            //      Candidate indices unique across all 64 quarters. ----
            const unsigned long long mb = __ballot(si == ci);
            const int wl = (__ffsll(mb) - 1) & 63;
            qxf = __int_as_float(
                __builtin_amdgcn_readlane(__float_as_int(px), wl));
            qyf = __int_as_float(
                __builtin_amdgcn_readlane(__float_as_int(py), wl));
            qzf = __int_as_float(
                __builtin_amdgcn_readlane(__float_as_int(pz), wl));

            // ---- LDS mailbox: 3 tagged coord words ----
            if (lane < 3) {
                const unsigned coord =
                    (lane == 0) ? (unsigned)__float_as_int(qxf)
                  : (lane == 1) ? (unsigned)__float_as_int(qyf)
                                : (unsigned)__float_as_int(qzf);
                __hip_atomic_store(&s_mail[par][lane],
                                   ((unsigned long long)coord << 32)
                                 | (unsigned long long)tag,
                                   __ATOMIC_RELAXED,
                                   __HIP_MEMORY_SCOPE_WORKGROUP);
            }
        }

        // ---- winner coords from registers/LDS; no dependent P[wi] fetch ----
        qx = (double)qxf; qy = (double)qyf; qz = (double)qzf;
    }
}

extern "C" void kernel_launch(void* const* d_in, const int* in_sizes, int n_in,
                              void* d_out, int out_size, void* d_ws, size_t ws_size,
                              hipStream_t stream) {
    (void)in_sizes; (void)n_in; (void)out_size;
    // d_in[0] = npoints (scalar, fixed 2048 per setup), d_in[1] = t_in
    const float* t_in = (const float*)d_in[1];
    int* out = (int*)d_out;
    unsigned long long* slots = (unsigned long long*)d_ws;  // 33 KB used
    int allow_fast = (ws_size >= (XID_OFF_U64 * 8 + NBATCH * KBLK * 4)) ? 1 : 0;

    dim3 grid(NBATCH * KBLK);
    dim3 block(THREADS);
    void* args[] = { (void*)&t_in, (void*)&out, (void*)&slots,
                     (void*)&allow_fast };
    hipLaunchCooperativeKernel((const void*)fps_kernel, grid, block, args, 0, stream);
}

// Round 6
// 4300.667 us; speedup vs baseline: 2.9939x; 2.9939x over previous
//
#include <hip/hip_runtime.h>
#include <stdint.h>

// Farthest point sampling: b=16, n=65536, npoints=2048. Full-f64 decision
// pipeline (R5: harness ref is float64 ground-truth recompute; R5-R21 absmax 0).
//
// R22 = R20 (4.31 ms, the proven config) + poll loads at DEVICE scope (sc1)
// instead of SYSTEM scope (sc0 sc1).
// R21's post-mortem: XCD-local (sc0-only) polling is a stale-read trap --
// the poll loads were served by a level that never sees the remote store;
// all 48 rounds failed every iteration and the AGENT-atomic escalation
// (device scope) rescued correctness at 3x cost. Lesson: the only proven
// visibility-safe read paths are device scope and stronger. The R20 poll
// used system scope (sc0 sc1), which is STRONGER than needed: publishers
// are AGENT-scope stores, and the long-proven escalation spin is
// device-scope loads. R22 drops the polls to sc1-only (same encoding class
// as the escalation spin) to shed the system-coherence surcharge per round.
// Single-flag change; everything else R20 byte-identical.
// Tripwire: WRITE_SIZE must stay exactly 65632 KB. FETCH delta is the
// probe: R21 showed poll mechanism drives FETCH (23 GB -> 6 GB).
//
// Structure (validated R16-R20): 16 blocks x 256 thr per batch; pre-widened
// f64 coords (cvt paid once); DPP/permlane argmax butterflies (xor1/xor2
// quad_perm, row_half_mirror, row_mirror, ds_swizzle xor16,
// permlane32_swap); per-wave publish of 16-B quarters (4 per 64-B line,
// same-CU writers); wave0 polls 64 quarters (lane i watches quarter i,
// own-quarter register substitution), s_sleep(12) then 32 rounds of one
// global_load_dwordx4 sc1 per round, escalating to the proven agent
// atomic-pair spin; speculative coord prefetch before the detect butterfly
// + ballot(si==ci) + readlane broadcast; waves1-3 spin on 3 self-tagged
// LDS coord words {x|tag,y|tag,z|tag}. Parity double-buffer, unique 16-bit
// tags (poison 0 unmatchable), skew <= 1 iteration.

#define NBATCH   16
#define NPTS     65536
#define NPOINTS  2048
#define KBLK     16                  // blocks per batch
#define THREADS  256
#define PPB      4096                // points per block
#define PPT      16                  // points per thread
#define QPB      4                   // quarters (waves) per block
#define SLOT_U64 2                   // 16 B per wave-quarter
#define REGION_U64 (KBLK * QPB * SLOT_U64) // 128 u64 = 1 KB per (parity,batch)

#define TAGOK(w) (((unsigned)((w) >> 16) & 0xFFFFu) == tag)

typedef unsigned int uint4v __attribute__((ext_vector_type(4)));
typedef unsigned int uint2v __attribute__((ext_vector_type(2)));

// One 16-B device-scope load covering both quarter words. Device scope
// (sc1) is the same visibility class as the proven AGENT atomic escalation
// spin -- sufficient for AGENT-scope publishers, cheaper than system scope.
__device__ __forceinline__ void load_slot16(const unsigned long long* p,
                                            unsigned long long& w0,
                                            unsigned long long& w1) {
    uint4v r;
    asm volatile("global_load_dwordx4 %0, %1, off sc1\n\t"
                 "s_waitcnt vmcnt(0)"
                 : "=v"(r) : "v"(p) : "memory");
    w0 = ((unsigned long long)r.y << 32) | r.x;
    w1 = ((unsigned long long)r.w << 32) | r.z;
}

// ---- argmax butterfly stages: (d,i) <- winner of self and partner ----
__device__ __forceinline__ void red_combine(double& d, int& i,
                                            double od, int oi) {
    const bool t = (od > d) || (od == d && oi < i);
    d = t ? od : d; i = t ? oi : i;
}

template <int CTRL>
__device__ __forceinline__ void red_dpp(double& d, int& i) {
    const int hi = __double2hiint(d), lo = __double2loint(d);
    const int ohi = __builtin_amdgcn_update_dpp(hi, hi, CTRL, 0xF, 0xF, false);
    const int olo = __builtin_amdgcn_update_dpp(lo, lo, CTRL, 0xF, 0xF, false);
    const int oi  = __builtin_amdgcn_update_dpp(i,  i,  CTRL, 0xF, 0xF, false);
    red_combine(d, i, __hiloint2double(ohi, olo), oi);
}

__device__ __forceinline__ void red_swz16(double& d, int& i) {
    // ds_swizzle BitMode xor16: offset = (16<<10) | 0x1F = 0x401F
    const int ohi = __builtin_amdgcn_ds_swizzle(__double2hiint(d), 0x401F);
    const int olo = __builtin_amdgcn_ds_swizzle(__double2loint(d), 0x401F);
    const int oi  = __builtin_amdgcn_ds_swizzle(i, 0x401F);
    red_combine(d, i, __hiloint2double(ohi, olo), oi);
}

__device__ __forceinline__ void red_x32(double& d, int& i, bool hi_half) {
    // permlane32_swap(v,v): partner = hi_half ? r[0] : r[1].
    const unsigned hi = (unsigned)__double2hiint(d);
    const unsigned lo = (unsigned)__double2loint(d);
    uint2v rh = __builtin_amdgcn_permlane32_swap(hi, hi, false, false);
    uint2v rl = __builtin_amdgcn_permlane32_swap(lo, lo, false, false);
    uint2v ri = __builtin_amdgcn_permlane32_swap((unsigned)i, (unsigned)i,
                                                 false, false);
    const int ohi = (int)(hi_half ? rh[0] : rh[1]);
    const int olo = (int)(hi_half ? rl[0] : rl[1]);
    const int oi  = (int)(hi_half ? ri[0] : ri[1]);
    red_combine(d, i, __hiloint2double(ohi, olo), oi);
}

// Full 64-lane argmax (all lanes end with the global winner). Stage order
// matters: mirrors rely on prior quad/8-group uniformity.
__device__ __forceinline__ void argmax64(double& d, int& i, bool hi_half) {
    red_dpp<0xB1>(d, i);    // xor1  (quad_perm 1,0,3,2)
    red_dpp<0x4E>(d, i);    // xor2  (quad_perm 2,3,0,1)
    red_dpp<0x141>(d, i);   // i^7 row_half_mirror -> 8-max
    red_dpp<0x140>(d, i);   // i^15 row_mirror     -> 16-max
    red_swz16(d, i);        // xor16               -> 32-max
    red_x32(d, i, hi_half); // xor32               -> 64-max
}

__global__ __launch_bounds__(THREADS, 1)
void fps_kernel(const float* __restrict__ pts, int* __restrict__ out,
                unsigned long long* __restrict__ slots)
{
    const int bid  = blockIdx.x;
    const int g    = bid & 15;       // batch (XCD co-location swizzle)
    const int blk  = bid >> 4;       // block within batch, 0..15
    const int tid  = threadIdx.x;
    const int lane = tid & 63;
    const int wave = tid >> 6;       // 0..3
    const bool hi_half = (lane >= 32);

    const float* __restrict__ P = pts + (size_t)g * (NPTS * 3);

    // mailbox: [par][k] = coord_k|tag for k=0,1,2 (x,y,z); [3] unused pad
    __shared__ unsigned long long s_mail[2][4];

    // Pre-widened f64 coords (cvt paid ONCE, not per iteration) + f64 dist.
    double xd[PPT], yd[PPT], zd[PPT], dist[PPT];
    const int base = blk * PPB;
#pragma unroll
    for (int j = 0; j < PPT; ++j) {
        const int idx = base + j * THREADS + tid;
        xd[j] = (double)P[idx * 3 + 0];
        yd[j] = (double)P[idx * 3 + 1];
        zd[j] = (double)P[idx * 3 + 2];
        dist[j] = 1e10;              // never survives iteration 0
    }
    if (tid < 8) ((unsigned long long*)s_mail)[tid] = 0ull;  // tags never 0
    __syncthreads();                 // once, before the loop

    double qx = (double)P[0], qy = (double)P[1], qz = (double)P[2];
    if (blk == 0 && tid == 0) out[g * NPOINTS] = 0;

    for (int it = 0; it < NPOINTS - 1; ++it) {
        // ---- f64 min-dist update + thread-local argmax (first-max) ----
        double bd = -1.0;
        int    bi = 0x7FFFFFFF;
        {
#pragma clang fp contract(off)
#pragma unroll
            for (int j = 0; j < PPT; ++j) {
                const double dx = xd[j] - qx;
                const double dy = yd[j] - qy;
                const double dz = zd[j] - qz;
                const double d  = (dx * dx + dy * dy) + dz * dz;
                const double nd = fmin(dist[j], d);
                dist[j] = nd;
                const bool t = nd > bd;          // strict: first-max kept
                bd = t ? nd : bd;
                bi = t ? (base + j * THREADS + tid) : bi;
            }
        }

        // ---- 64-lane argmax butterfly (DPP/permlane transport) ----
        argmax64(bd, bi, hi_half);

        const unsigned tag = (unsigned)(it + 1);
        const int par = it & 1;
        unsigned long long* rb =
            slots + (size_t)(par * NBATCH + g) * REGION_U64;

        // ---- this wave's quarter words (publish + own substitution) ----
        const unsigned long long B =
            (unsigned long long)__double_as_longlong(bd);
        const unsigned long long TI =
              ((unsigned long long)tag << 16)
            | (unsigned long long)((unsigned)bi & 0xFFFFu);
        const unsigned long long own0 = ((B >> 32) << 32) | TI;
        const unsigned long long own1 = ((B & 0xFFFFFFFFull) << 32) | TI;

        // ---- per-wave publish: straight from butterfly to global store,
        //      no LDS post / gather / combine funnel ----
        if (lane < 2) {
            __hip_atomic_store(rb + (blk * QPB + wave) * SLOT_U64 + lane,
                               (lane == 0) ? own0 : own1,
                               __ATOMIC_RELAXED,
                               __HIP_MEMORY_SCOPE_AGENT);
        }

        float qxf, qyf, qzf;         // this iteration's winner coords (f32)

        if (wave != 0) {
            // ---- winner coords from LDS (3 self-tagged words). This IS
            //      the rendezvous: tags==it+1 only after wave0 broadcast;
            //      parity leftovers carry tag it-1 -> no false positive ----
            unsigned long long f1, f2, f3;
            int guard = 0;
            bool okm;
            do {
                f1 = __hip_atomic_load(&s_mail[par][0], __ATOMIC_RELAXED,
                                       __HIP_MEMORY_SCOPE_WORKGROUP);
                f2 = __hip_atomic_load(&s_mail[par][1], __ATOMIC_RELAXED,
                                       __HIP_MEMORY_SCOPE_WORKGROUP);
                f3 = __hip_atomic_load(&s_mail[par][2], __ATOMIC_RELAXED,
                                       __HIP_MEMORY_SCOPE_WORKGROUP);
                okm = ((unsigned)f1 == tag) & ((unsigned)f2 == tag)
                    & ((unsigned)f3 == tag);
            } while (!okm && ++guard < (1 << 20));
            qxf = __int_as_float((int)(f1 >> 32));
            qyf = __int_as_float((int)(f2 >> 32));
            qzf = __int_as_float((int)(f3 >> 32));
        } else {
            // ---- wave0: poll all 64 quarters, lane i watches quarter i
            //      (16-B stride, contiguous 1 KB = 16 lines).
            //      Own quarter (lane == blk*4) from registers. ----
            unsigned long long* sp = rb + lane * SLOT_U64;
            const bool own = (lane == blk * QPB);
            unsigned long long l0 = own0, l1 = own1;
            bool ok = own;
            __builtin_amdgcn_s_sleep(12);  // ~768 cy: skip guaranteed-miss rounds
            int g1 = 0;
            while (!ok && g1 < 32) {
                load_slot16(sp, l0, l1);
                ok = TAGOK(l0) & TAGOK(l1);
                ++g1;
            }
            int g2 = 0;
            while (!ok) {
                // escalation: proven agent atomic-pair spin
                l0 = __hip_atomic_load(sp + 0, __ATOMIC_RELAXED,
                                       __HIP_MEMORY_SCOPE_AGENT);
                l1 = __hip_atomic_load(sp + 1, __ATOMIC_RELAXED,
                                       __HIP_MEMORY_SCOPE_AGENT);
                ok = TAGOK(l0) & TAGOK(l1);
                if (++g2 > (1 << 20)) break;   // fail loud, never hang
            }

            double cd = __longlong_as_double(
                (long long)(((l0 >> 32) << 32) | (l1 >> 32)));
            int    ci = (int)(l0 & 0xFFFFull);

            // ---- speculative prefetch of THIS lane's candidate coords:
            //      issued before the butterfly so the L2 hit overlaps it ----
            const int    si = ci;
            const float* pc = P + (size_t)(unsigned)si * 3;
            const float px = pc[0];
            const float py = pc[1];
            const float pz = pc[2];

            // ---- 64-quarter argmax butterfly (DPP/permlane transport) ----
            argmax64(cd, ci, hi_half);

            // ---- out write: independent of the coord chain ----
            if (lane == 0 && blk == 0) out[g * NPOINTS + it + 1] = ci;

            // ---- winning lane -> broadcast its prefetched coords.
            //      Candidate indices unique across all 64 quarters
            //      (disjoint tid partitions). ----
            const unsigned long long mb = __ballot(si == ci);
            const int wl = (__ffsll(mb) - 1) & 63;
            qxf = __int_as_float(
                __builtin_amdgcn_readlane(__float_as_int(px), wl));
            qyf = __int_as_float(
                __builtin_amdgcn_readlane(__float_as_int(py), wl));
            qzf = __int_as_float(
                __builtin_amdgcn_readlane(__float_as_int(pz), wl));

            // ---- LDS mailbox: 3 tagged coord words ----
            if (lane < 3) {
                const unsigned coord =
                    (lane == 0) ? (unsigned)__float_as_int(qxf)
                  : (lane == 1) ? (unsigned)__float_as_int(qyf)
                                : (unsigned)__float_as_int(qzf);
                __hip_atomic_store(&s_mail[par][lane],
                                   ((unsigned long long)coord << 32)
                                 | (unsigned long long)tag,
                                   __ATOMIC_RELAXED,
                                   __HIP_MEMORY_SCOPE_WORKGROUP);
            }
        }

        // ---- winner coords from registers/LDS; no dependent P[wi] fetch ----
        qx = (double)qxf; qy = (double)qyf; qz = (double)qzf;
    }
}

extern "C" void kernel_launch(void* const* d_in, const int* in_sizes, int n_in,
                              void* d_out, int out_size, void* d_ws, size_t ws_size,
                              hipStream_t stream) {
    (void)in_sizes; (void)n_in; (void)out_size; (void)ws_size;
    // d_in[0] = npoints (scalar, fixed 2048 per setup), d_in[1] = t_in
    const float* t_in = (const float*)d_in[1];
    int* out = (int*)d_out;
    unsigned long long* slots = (unsigned long long*)d_ws;  // 32 KB used

    dim3 grid(NBATCH * KBLK);
    dim3 block(THREADS);
    void* args[] = { (void*)&t_in, (void*)&out, (void*)&slots };
    hipLaunchCooperativeKernel((const void*)fps_kernel, grid, block, args, 0, stream);
}

// Round 7
// 4264.343 us; speedup vs baseline: 3.0194x; 1.0085x over previous
//
#include <hip/hip_runtime.h>
#include <stdint.h>

// Farthest point sampling: b=16, n=65536, npoints=2048. Full-f64 decision
// pipeline (R5: harness ref is float64 ground-truth recompute; R5-R22 absmax 0).
//
// R23 = R22 (4.30 ms) + ATOMIC publish (global_atomic_swap_x2, no-return)
// replacing the sc1 global stores.
// Wait-model (from R20-R22 evidence + FETCH units audit): FETCH is ~11.3
// KB/iter == slot lines fetched ONCE per iteration -> readers spin on a
// STALE local-cache copy (fast rounds, no beyond-L2 traffic; why R22's
// poll-scope change was neutral) until the publisher's store finally
// transits writeback/ordering queues to the coherence point and the sharer
// invalidation lands (~2500-3500 cy). The poll side cannot fix this; the
// store side can: an atomic RMW executes AT the coherence point and its
// sharer invalidation is part of the operation, not a lazy writeback.
// Single-writer-per-word + swap == store semantics, so correctness is
// unchanged; all guards/escalation stay -> failure mode remains slow-not-
// wrong. Prediction: dur ~3.3-3.7 ms if transit-collapse is right; neutral
// if atomics propagate no faster (then next probe is reader-side).
//
// Structure (validated R16-R22): 16 blocks x 256 thr per batch; pre-widened
// f64 coords (cvt paid once); DPP/permlane argmax butterflies (xor1/xor2
// quad_perm, row_half_mirror, row_mirror, ds_swizzle xor16,
// permlane32_swap); per-wave publish of 16-B quarters (4 per 64-B line,
// same-CU writers); wave0 polls 64 quarters (lane i watches quarter i,
// own-quarter register substitution), s_sleep(12) then 32 rounds of one
// global_load_dwordx4 sc1 per round, escalating to the proven agent
// atomic-pair spin; speculative coord prefetch before the detect butterfly
// + ballot(si==ci) + readlane broadcast; waves1-3 spin on 3 self-tagged
// LDS coord words {x|tag,y|tag,z|tag}. Parity double-buffer, unique 16-bit
// tags (poison 0 unmatchable), skew <= 1 iteration.

#define NBATCH   16
#define NPTS     65536
#define NPOINTS  2048
#define KBLK     16                  // blocks per batch
#define THREADS  256
#define PPB      4096                // points per block
#define PPT      16                  // points per thread
#define QPB      4                   // quarters (waves) per block
#define SLOT_U64 2                   // 16 B per wave-quarter
#define REGION_U64 (KBLK * QPB * SLOT_U64) // 128 u64 = 1 KB per (parity,batch)

#define TAGOK(w) (((unsigned)((w) >> 16) & 0xFFFFu) == tag)

typedef unsigned int uint4v __attribute__((ext_vector_type(4)));
typedef unsigned int uint2v __attribute__((ext_vector_type(2)));

// One 16-B device-scope load covering both quarter words.
__device__ __forceinline__ void load_slot16(const unsigned long long* p,
                                            unsigned long long& w0,
                                            unsigned long long& w1) {
    uint4v r;
    asm volatile("global_load_dwordx4 %0, %1, off sc1\n\t"
                 "s_waitcnt vmcnt(0)"
                 : "=v"(r) : "v"(p) : "memory");
    w0 = ((unsigned long long)r.y << 32) | r.x;
    w1 = ((unsigned long long)r.w << 32) | r.z;
}

// ---- argmax butterfly stages: (d,i) <- winner of self and partner ----
__device__ __forceinline__ void red_combine(double& d, int& i,
                                            double od, int oi) {
    const bool t = (od > d) || (od == d && oi < i);
    d = t ? od : d; i = t ? oi : i;
}

template <int CTRL>
__device__ __forceinline__ void red_dpp(double& d, int& i) {
    const int hi = __double2hiint(d), lo = __double2loint(d);
    const int ohi = __builtin_amdgcn_update_dpp(hi, hi, CTRL, 0xF, 0xF, false);
    const int olo = __builtin_amdgcn_update_dpp(lo, lo, CTRL, 0xF, 0xF, false);
    const int oi  = __builtin_amdgcn_update_dpp(i,  i,  CTRL, 0xF, 0xF, false);
    red_combine(d, i, __hiloint2double(ohi, olo), oi);
}

__device__ __forceinline__ void red_swz16(double& d, int& i) {
    // ds_swizzle BitMode xor16: offset = (16<<10) | 0x1F = 0x401F
    const int ohi = __builtin_amdgcn_ds_swizzle(__double2hiint(d), 0x401F);
    const int olo = __builtin_amdgcn_ds_swizzle(__double2loint(d), 0x401F);
    const int oi  = __builtin_amdgcn_ds_swizzle(i, 0x401F);
    red_combine(d, i, __hiloint2double(ohi, olo), oi);
}

__device__ __forceinline__ void red_x32(double& d, int& i, bool hi_half) {
    // permlane32_swap(v,v): partner = hi_half ? r[0] : r[1].
    const unsigned hi = (unsigned)__double2hiint(d);
    const unsigned lo = (unsigned)__double2loint(d);
    uint2v rh = __builtin_amdgcn_permlane32_swap(hi, hi, false, false);
    uint2v rl = __builtin_amdgcn_permlane32_swap(lo, lo, false, false);
    uint2v ri = __builtin_amdgcn_permlane32_swap((unsigned)i, (unsigned)i,
                                                 false, false);
    const int ohi = (int)(hi_half ? rh[0] : rh[1]);
    const int olo = (int)(hi_half ? rl[0] : rl[1]);
    const int oi  = (int)(hi_half ? ri[0] : ri[1]);
    red_combine(d, i, __hiloint2double(ohi, olo), oi);
}

// Full 64-lane argmax (all lanes end with the global winner). Stage order
// matters: mirrors rely on prior quad/8-group uniformity.
__device__ __forceinline__ void argmax64(double& d, int& i, bool hi_half) {
    red_dpp<0xB1>(d, i);    // xor1  (quad_perm 1,0,3,2)
    red_dpp<0x4E>(d, i);    // xor2  (quad_perm 2,3,0,1)
    red_dpp<0x141>(d, i);   // i^7 row_half_mirror -> 8-max
    red_dpp<0x140>(d, i);   // i^15 row_mirror     -> 16-max
    red_swz16(d, i);        // xor16               -> 32-max
    red_x32(d, i, hi_half); // xor32               -> 64-max
}

__global__ __launch_bounds__(THREADS, 1)
void fps_kernel(const float* __restrict__ pts, int* __restrict__ out,
                unsigned long long* __restrict__ slots)
{
    const int bid  = blockIdx.x;
    const int g    = bid & 15;       // batch (XCD co-location swizzle)
    const int blk  = bid >> 4;       // block within batch, 0..15
    const int tid  = threadIdx.x;
    const int lane = tid & 63;
    const int wave = tid >> 6;       // 0..3
    const bool hi_half = (lane >= 32);

    const float* __restrict__ P = pts + (size_t)g * (NPTS * 3);

    // mailbox: [par][k] = coord_k|tag for k=0,1,2 (x,y,z); [3] unused pad
    __shared__ unsigned long long s_mail[2][4];

    // Pre-widened f64 coords (cvt paid ONCE, not per iteration) + f64 dist.
    double xd[PPT], yd[PPT], zd[PPT], dist[PPT];
    const int base = blk * PPB;
#pragma unroll
    for (int j = 0; j < PPT; ++j) {
        const int idx = base + j * THREADS + tid;
        xd[j] = (double)P[idx * 3 + 0];
        yd[j] = (double)P[idx * 3 + 1];
        zd[j] = (double)P[idx * 3 + 2];
        dist[j] = 1e10;              // never survives iteration 0
    }
    if (tid < 8) ((unsigned long long*)s_mail)[tid] = 0ull;  // tags never 0
    __syncthreads();                 // once, before the loop

    double qx = (double)P[0], qy = (double)P[1], qz = (double)P[2];
    if (blk == 0 && tid == 0) out[g * NPOINTS] = 0;

    for (int it = 0; it < NPOINTS - 1; ++it) {
        // ---- f64 min-dist update + thread-local argmax (first-max) ----
        double bd = -1.0;
        int    bi = 0x7FFFFFFF;
        {
#pragma clang fp contract(off)
#pragma unroll
            for (int j = 0; j < PPT; ++j) {
                const double dx = xd[j] - qx;
                const double dy = yd[j] - qy;
                const double dz = zd[j] - qz;
                const double d  = (dx * dx + dy * dy) + dz * dz;
                const double nd = fmin(dist[j], d);
                dist[j] = nd;
                const bool t = nd > bd;          // strict: first-max kept
                bd = t ? nd : bd;
                bi = t ? (base + j * THREADS + tid) : bi;
            }
        }

        // ---- 64-lane argmax butterfly (DPP/permlane transport) ----
        argmax64(bd, bi, hi_half);

        const unsigned tag = (unsigned)(it + 1);
        const int par = it & 1;
        unsigned long long* rb =
            slots + (size_t)(par * NBATCH + g) * REGION_U64;

        // ---- this wave's quarter words (publish + own substitution) ----
        const unsigned long long B =
            (unsigned long long)__double_as_longlong(bd);
        const unsigned long long TI =
              ((unsigned long long)tag << 16)
            | (unsigned long long)((unsigned)bi & 0xFFFFu);
        const unsigned long long own0 = ((B >> 32) << 32) | TI;
        const unsigned long long own1 = ((B & 0xFFFFFFFFull) << 32) | TI;

        // ---- per-wave publish via no-return ATOMIC swap: executed AT the
        //      coherence point; sharer invalidation is part of the op, not
        //      a lazy writeback. Single writer per word -> swap == store ----
        if (lane < 2) {
            unsigned long long* dst =
                rb + (blk * QPB + wave) * SLOT_U64 + lane;
            const unsigned long long v = (lane == 0) ? own0 : own1;
            asm volatile("global_atomic_swap_x2 %0, %1, off"
                         :: "v"(dst), "v"(v) : "memory");
        }

        float qxf, qyf, qzf;         // this iteration's winner coords (f32)

        if (wave != 0) {
            // ---- winner coords from LDS (3 self-tagged words). This IS
            //      the rendezvous: tags==it+1 only after wave0 broadcast;
            //      parity leftovers carry tag it-1 -> no false positive ----
            unsigned long long f1, f2, f3;
            int guard = 0;
            bool okm;
            do {
                f1 = __hip_atomic_load(&s_mail[par][0], __ATOMIC_RELAXED,
                                       __HIP_MEMORY_SCOPE_WORKGROUP);
                f2 = __hip_atomic_load(&s_mail[par][1], __ATOMIC_RELAXED,
                                       __HIP_MEMORY_SCOPE_WORKGROUP);
                f3 = __hip_atomic_load(&s_mail[par][2], __ATOMIC_RELAXED,
                                       __HIP_MEMORY_SCOPE_WORKGROUP);
                okm = ((unsigned)f1 == tag) & ((unsigned)f2 == tag)
                    & ((unsigned)f3 == tag);
            } while (!okm && ++guard < (1 << 20));
            qxf = __int_as_float((int)(f1 >> 32));
            qyf = __int_as_float((int)(f2 >> 32));
            qzf = __int_as_float((int)(f3 >> 32));
        } else {
            // ---- wave0: poll all 64 quarters, lane i watches quarter i
            //      (16-B stride, contiguous 1 KB = 16 lines).
            //      Own quarter (lane == blk*4) from registers. ----
            unsigned long long* sp = rb + lane * SLOT_U64;
            const bool own = (lane == blk * QPB);
            unsigned long long l0 = own0, l1 = own1;
            bool ok = own;
            __builtin_amdgcn_s_sleep(12);  // ~768 cy: skip guaranteed-miss rounds
            int g1 = 0;
            while (!ok && g1 < 32) {
                load_slot16(sp, l0, l1);
                ok = TAGOK(l0) & TAGOK(l1);
                ++g1;
            }
            int g2 = 0;
            while (!ok) {
                // escalation: proven agent atomic-pair spin
                l0 = __hip_atomic_load(sp + 0, __ATOMIC_RELAXED,
                                       __HIP_MEMORY_SCOPE_AGENT);
                l1 = __hip_atomic_load(sp + 1, __ATOMIC_RELAXED,
                                       __HIP_MEMORY_SCOPE_AGENT);
                ok = TAGOK(l0) & TAGOK(l1);
                if (++g2 > (1 << 20)) break;   // fail loud, never hang
            }

            double cd = __longlong_as_double(
                (long long)(((l0 >> 32) << 32) | (l1 >> 32)));
            int    ci = (int)(l0 & 0xFFFFull);

            // ---- speculative prefetch of THIS lane's candidate coords:
            //      issued before the butterfly so the L2 hit overlaps it ----
            const int    si = ci;
            const float* pc = P + (size_t)(unsigned)si * 3;
            const float px = pc[0];
            const float py = pc[1];
            const float pz = pc[2];

            // ---- 64-quarter argmax butterfly (DPP/permlane transport) ----
            argmax64(cd, ci, hi_half);

            // ---- out write: independent of the coord chain ----
            if (lane == 0 && blk == 0) out[g * NPOINTS + it + 1] = ci;

            // ---- winning lane -> broadcast its prefetched coords.
            //      Candidate indices unique across all 64 quarters
            //      (disjoint tid partitions). ----
            const unsigned long long mb = __ballot(si == ci);
            const int wl = (__ffsll(mb) - 1) & 63;
            qxf = __int_as_float(
                __builtin_amdgcn_readlane(__float_as_int(px), wl));
            qyf = __int_as_float(
                __builtin_amdgcn_readlane(__float_as_int(py), wl));
            qzf = __int_as_float(
                __builtin_amdgcn_readlane(__float_as_int(pz), wl));

            // ---- LDS mailbox: 3 tagged coord words ----
            if (lane < 3) {
                const unsigned coord =
                    (lane == 0) ? (unsigned)__float_as_int(qxf)
                  : (lane == 1) ? (unsigned)__float_as_int(qyf)
                                : (unsigned)__float_as_int(qzf);
                __hip_atomic_store(&s_mail[par][lane],
                                   ((unsigned long long)coord << 32)
                                 | (unsigned long long)tag,
                                   __ATOMIC_RELAXED,
                                   __HIP_MEMORY_SCOPE_WORKGROUP);
            }
        }

        // ---- winner coords from registers/LDS; no dependent P[wi] fetch ----
        qx = (double)qxf; qy = (double)qyf; qz = (double)qzf;
    }
}

extern "C" void kernel_launch(void* const* d_in, const int* in_sizes, int n_in,
                              void* d_out, int out_size, void* d_ws, size_t ws_size,
                              hipStream_t stream) {
    (void)in_sizes; (void)n_in; (void)out_size; (void)ws_size;
    // d_in[0] = npoints (scalar, fixed 2048 per setup), d_in[1] = t_in
    const float* t_in = (const float*)d_in[1];
    int* out = (int*)d_out;
    unsigned long long* slots = (unsigned long long*)d_ws;  // 32 KB used

    dim3 grid(NBATCH * KBLK);
    dim3 block(THREADS);
    void* args[] = { (void*)&t_in, (void*)&out, (void*)&slots };
    hipLaunchCooperativeKernel((const void*)fps_kernel, grid, block, args, 0, stream);
}